// Round 4
// baseline (322.841 us; speedup 1.0000x reference)
//
#include <hip/hip_runtime.h>

// Problem constants (from reference)
#define VOCAB 32000
#define D     64
#define B     32
#define S     512
#define NCHUNK 8     // number of time chunks
#define CLEN   64    // chunk length (S / NCHUNK)

typedef float vf4 __attribute__((ext_vector_type(4)));

// ---------------------------------------------------------------------------
// Single fused kernel. Grid: B * NCHUNK * 4 = 1024 blocks, 256 threads
// = 16 i-rows x 16 jq (float4 over j).
//
// Block swizzle (CUs host blocks {n, n+256, n+512, n+768}):
//   c     = blk >> 7        -> a CU's 4 blocks span chunks {c, c+2, c+4, c+6}:
//                              balanced pre-scan work, stores flow from t~0
//                              on every CU (round-2's c=blk&7 aliased all four
//                              resident blocks to one c: 256 % 8 == 0).
//   b     = (blk >> 2) & 31 -> same b for all 4 resident blocks (emb-row
//                              L1/L2 locality; ~131 KB of hot rows per b).
//   iBase = (blk & 3) * 16
//
// Each block: (1) one coalesced load of x[b,:] into LDS (2 KB);
// (2) redundant pre-scan t = 0 .. c*CLEN-1 reading emb rows directly
//     (token from LDS, row from L1/L2; unroll-8 pipelines 8 independent
//     token->row chains over the ~200cy L2 latency; overlapped with other
//     blocks' stores anyway);
// (3) 64-step chunk writing every state, plain coalesced float4 stores
//     (wave = 1 KiB contiguous -> full-line writes, no RFO; fills achieve
//      6.2 TB/s on this path).
// ---------------------------------------------------------------------------
__global__ __launch_bounds__(256, 4) void qmn_fused(
    const int*  __restrict__ x,      // [B, S]
    const float* __restrict__ emb,   // [VOCAB, D]
    vf4*        __restrict__ out4)   // [B, S, D, D] as float4 over j
{
    const float DECAY = 0.9f;

    __shared__ int toks[S];

    int blk   = blockIdx.x;
    int c     = blk >> 7;
    int b     = (blk >> 2) & 31;
    int iBase = (blk & 3) * 16;

    int jq = threadIdx.x & 15;
    int i  = iBase + (threadIdx.x >> 4);

    // stage token ids for this batch: 512 ints, two coalesced loads
    {
        const int* xb = x + b * S;
        toks[threadIdx.x]       = xb[threadIdx.x];
        toks[threadIdx.x + 256] = xb[threadIdx.x + 256];
    }
    __syncthreads();

    // identity init
    vf4 rho;
    int j0 = jq * 4;
    rho.x = (i == j0 + 0) ? 1.0f : 0.0f;
    rho.y = (i == j0 + 1) ? 1.0f : 0.0f;
    rho.z = (i == j0 + 2) ? 1.0f : 0.0f;
    rho.w = (i == j0 + 3) ? 1.0f : 0.0f;

    const vf4* embv = (const vf4*)emb;   // [VOCAB, D/4]
    const int tStart = c * CLEN;

    // ---- pre-scan to the chunk boundary: no stores ----
    #pragma unroll 8
    for (int t = 0; t < tStart; ++t) {
        int tok = toks[t];                    // LDS broadcast (uniform addr)
        float ci = emb[tok * D + i];          // 4 lines/wave, broadcast
        vf4   cj = embv[tok * (D / 4) + jq];  // 256B row
        rho.x = rho.x * DECAY + ci * cj.x;
        rho.y = rho.y * DECAY + ci * cj.y;
        rho.z = rho.z * DECAY + ci * cj.z;
        rho.w = rho.w * DECAY + ci * cj.w;
    }

    // ---- main chunk: 64 steps, store every state ----
    vf4* outp = out4 + (((size_t)(b * S + tStart)) * D + i) * (D / 4) + jq;

    #pragma unroll 4
    for (int tt = 0; tt < CLEN; ++tt) {
        int tok = toks[tStart + tt];
        float ci = emb[tok * D + i];
        vf4   cj = embv[tok * (D / 4) + jq];
        rho.x = rho.x * DECAY + ci * cj.x;
        rho.y = rho.y * DECAY + ci * cj.y;
        rho.z = rho.z * DECAY + ci * cj.z;
        rho.w = rho.w * DECAY + ci * cj.w;
        *outp = rho;
        outp += D * (D / 4);                 // next t: +16 KiB
    }
}

// ---------------------------------------------------------------------------
// Launch
// ---------------------------------------------------------------------------
extern "C" void kernel_launch(void* const* d_in, const int* in_sizes, int n_in,
                              void* d_out, int out_size, void* d_ws, size_t ws_size,
                              hipStream_t stream) {
    const int*   x   = (const int*)d_in[0];     // [B, S] token ids
    const float* emb = (const float*)d_in[1];   // [VOCAB, D]
    vf4* out = (vf4*)d_out;                     // [B, S, D, D]

    qmn_fused<<<B * NCHUNK * 4, 256, 0, stream>>>(x, emb, out);
}